// Round 11
// baseline (665.433 us; speedup 1.0000x reference)
//
#include <hip/hip_runtime.h>
#include <hip/hip_bf16.h>

#define N_NODES 100000
#define N_EDGES 1600000
#define NFEAT 512
#define NHID 256
#define NCLS 64
#define KHOP 10
#define NPART 98  // (N_NODES + 1023) / 1024
#define BUFSZ ((size_t)N_NODES * NCLS)

typedef __attribute__((ext_vector_type(8))) short short8;
typedef __attribute__((ext_vector_type(4))) float f32x4;

__device__ __forceinline__ unsigned short f2b(float f) {
  union { float f; unsigned u; } v; v.f = f;
  unsigned r = v.u + 0x7FFFu + ((v.u >> 16) & 1u);
  return (unsigned short)(r >> 16);
}

// ---------------- graph preprocessing ----------------

__global__ __launch_bounds__(256) void k_zero(int* __restrict__ counts) {
  int i = blockIdx.x * 256 + threadIdx.x;
  if (i < N_NODES) counts[i] = 0;
}

__global__ __launch_bounds__(256) void k_count(const int* __restrict__ col,
                                               int* __restrict__ counts) {
  int e = blockIdx.x * 256 + threadIdx.x;
  if (e < N_EDGES) atomicAdd(&counts[col[e]], 1);
}

// ---- 3-phase coalesced exclusive scan of counts -> offs/cursor ----

__global__ __launch_bounds__(256) void k_reduce(const int* __restrict__ counts,
                                                int* __restrict__ partials) {
  int base = blockIdx.x * 1024 + threadIdx.x * 4;
  int4 c = make_int4(0, 0, 0, 0);
  if (base < N_NODES) c = *(const int4*)(counts + base);  // N % 4 == 0
  int s = c.x + c.y + c.z + c.w;
#pragma unroll
  for (int off = 32; off; off >>= 1) s += __shfl_xor(s, off, 64);
  __shared__ int wsum[4];
  int lane = threadIdx.x & 63, wave = threadIdx.x >> 6;
  if (lane == 0) wsum[wave] = s;
  __syncthreads();
  if (threadIdx.x == 0) partials[blockIdx.x] = wsum[0] + wsum[1] + wsum[2] + wsum[3];
}

__global__ __launch_bounds__(128) void k_scanp(int* __restrict__ partials,
                                               int* __restrict__ offs) {
  __shared__ int sm[128];
  int t = threadIdx.x;
  int v = (t < NPART) ? partials[t] : 0;
  sm[t] = v;
  __syncthreads();
  for (int off = 1; off < 128; off <<= 1) {
    int u = (t >= off) ? sm[t - off] : 0;
    __syncthreads();
    sm[t] += u;
    __syncthreads();
  }
  if (t < NPART) partials[t] = sm[t] - v;  // exclusive block prefix
  if (t == NPART - 1) offs[N_NODES] = sm[t];
}

__global__ __launch_bounds__(256) void k_scatter(const int* __restrict__ counts,
                                                 const int* __restrict__ partials,
                                                 int* __restrict__ offs,
                                                 int* __restrict__ cursor) {
  int t = threadIdx.x;
  int base = blockIdx.x * 1024 + t * 4;
  bool valid = base < N_NODES;
  int4 c = make_int4(0, 0, 0, 0);
  if (valid) c = *(const int4*)(counts + base);
  int s = c.x + c.y + c.z + c.w;
  int lane = t & 63, wave = t >> 6;
  int inc = s;
#pragma unroll
  for (int off = 1; off < 64; off <<= 1) {
    int u = __shfl_up(inc, off, 64);
    if (lane >= off) inc += u;
  }
  __shared__ int wsum[4];
  if (lane == 63) wsum[wave] = inc;
  __syncthreads();
  int pre = partials[blockIdx.x] + (inc - s);
  for (int w = 0; w < wave; w++) pre += wsum[w];
  if (valid) {
    int4 o;
    o.x = pre;
    o.y = o.x + c.x;
    o.z = o.y + c.y;
    o.w = o.z + c.z;
    *(int4*)(offs + base) = o;
    *(int4*)(cursor + base) = o;
  }
}

__global__ __launch_bounds__(256) void k_dinv(const int* __restrict__ counts,
                                              float* __restrict__ dinv) {
  int i = blockIdx.x * 256 + threadIdx.x;
  if (i < N_NODES) dinv[i] = rsqrtf((float)(counts[i] + 1));  // +1 self loop
}

__global__ __launch_bounds__(256) void k_fill(const int* __restrict__ ei,
                                              const float* __restrict__ dinv,
                                              int* __restrict__ cursor,
                                              int2* __restrict__ ew) {
  int e = blockIdx.x * 256 + threadIdx.x;
  if (e >= N_EDGES) return;
  int r = ei[e];
  int c = ei[N_EDGES + e];
  float w = dinv[r] * dinv[c];
  int p = atomicAdd(&cursor[c], 1);
  ew[p] = make_int2(r, __float_as_int(w));
}

// ---------------- transpose f32 [R][C] -> bf16 [C][R] (32x32 LDS tiles) ----------------

__global__ __launch_bounds__(256) void k_trans(const float* __restrict__ in,
                                               unsigned short* __restrict__ out,
                                               int R, int C) {
  __shared__ float sm[32][33];
  int tr0 = blockIdx.x * 32;
  int tc0 = blockIdx.y * 32;
#pragma unroll
  for (int i = 0; i < 4; i++) {
    int idx = threadIdx.x + i * 256;
    int r = idx >> 5, c = idx & 31;
    sm[r][c] = in[(size_t)(tr0 + r) * C + tc0 + c];
  }
  __syncthreads();
#pragma unroll
  for (int i = 0; i < 4; i++) {
    int idx = threadIdx.x + i * 256;
    int c = idx >> 5, r = idx & 31;
    out[(size_t)(tc0 + c) * R + tr0 + r] = f2b(sm[r][c]);
  }
}

// ---------------- MLP: GEMM1 (x@W1+b1, relu -> bf16 h1) ----------------
// BM=128, BN=256 (full hidden), BK=32; 8 waves (2x4), wave tile 64x64.
// SINGLE-buffered LDS (30.7 KB -> 4 blocks/CU = 32 waves/CU), reg prefetch of
// tile t+1 issued before the barriers; TLP (8 waves/SIMD) hides HBM latency.
// Tried and REJECTED:
//   R6 depth-2 reg pipeline: VGPR 56->76, occ 33->18.5%, slower.
//   R9 stride 34 (68B rows): breaks ds_*_b128 16B alignment, slower.
//   R4-R10 double-buffer (61.4KB LDS): 2 blocks/CU, latency-bound at 110 us.

__global__ __launch_bounds__(512) void k_gemm1(const float* __restrict__ x,
                                               const unsigned short* __restrict__ W1T,
                                               const float* __restrict__ b1,
                                               unsigned short* __restrict__ h1) {
  __shared__ unsigned short As[128 * 40];
  __shared__ unsigned short Bs[256 * 40];
  const int tid = threadIdx.x;
  const int r0 = blockIdx.x * 128;
  const int wave = tid >> 6, lane = tid & 63;
  const int wm = wave >> 2, wn = wave & 3;
  const int rr = lane & 15, kg = lane >> 4;
  const int arow = tid >> 3, akq = tid & 7;  // A rows [0,64)+[64,128)
  const int brow = tid >> 2, bq = tid & 3;   // B rows [0,128)+[128,256)

  f32x4 acc[4][4] = {};
  float4 av0, av1;
  int4 bv0, bv1;

#define G1_LOAD(K0)                                                                      \
  do {                                                                                   \
    av0 = make_float4(0.f, 0.f, 0.f, 0.f);                                               \
    av1 = av0;                                                                           \
    if (r0 + arow < N_NODES)                                                             \
      av0 = *(const float4*)(x + (size_t)(r0 + arow) * NFEAT + (K0) + akq * 4);          \
    if (r0 + arow + 64 < N_NODES)                                                        \
      av1 = *(const float4*)(x + (size_t)(r0 + arow + 64) * NFEAT + (K0) + akq * 4);     \
    bv0 = *(const int4*)(W1T + (size_t)brow * NFEAT + (K0) + bq * 8);                    \
    bv1 = *(const int4*)(W1T + (size_t)(brow + 128) * NFEAT + (K0) + bq * 8);            \
  } while (0)

#define G1_STORE()                                                                       \
  do {                                                                                   \
    uint2 p0, p1;                                                                        \
    p0.x = (unsigned)f2b(av0.x) | ((unsigned)f2b(av0.y) << 16);                          \
    p0.y = (unsigned)f2b(av0.z) | ((unsigned)f2b(av0.w) << 16);                          \
    p1.x = (unsigned)f2b(av1.x) | ((unsigned)f2b(av1.y) << 16);                          \
    p1.y = (unsigned)f2b(av1.z) | ((unsigned)f2b(av1.w) << 16);                          \
    *(uint2*)&As[arow * 40 + akq * 4] = p0;                                              \
    *(uint2*)&As[(arow + 64) * 40 + akq * 4] = p1;                                       \
    *(int4*)&Bs[brow * 40 + bq * 8] = bv0;                                               \
    *(int4*)&Bs[(brow + 128) * 40 + bq * 8] = bv1;                                       \
  } while (0)

  G1_LOAD(0);

  for (int t = 0; t < 16; t++) {
    G1_STORE();                         // tile t regs -> LDS
    if (t < 15) G1_LOAD((t + 1) * 32);  // issue next tile's loads (in flight over MFMA)
    __syncthreads();                    // tile t visible to all waves

    short8 a[4], b[4];
#pragma unroll
    for (int mf = 0; mf < 4; mf++)
      a[mf] = *(const short8*)&As[(wm * 64 + mf * 16 + rr) * 40 + kg * 8];
#pragma unroll
    for (int nf = 0; nf < 4; nf++)
      b[nf] = *(const short8*)&Bs[(wn * 64 + nf * 16 + rr) * 40 + kg * 8];
#pragma unroll
    for (int mf = 0; mf < 4; mf++)
#pragma unroll
      for (int nf = 0; nf < 4; nf++)
        acc[mf][nf] = __builtin_amdgcn_mfma_f32_16x16x32_bf16(a[mf], b[nf], acc[mf][nf], 0, 0, 0);

    __syncthreads();                    // all reads done before next store
  }

  // epilogue: +b1, relu, bf16 store
#pragma unroll
  for (int mf = 0; mf < 4; mf++) {
#pragma unroll
    for (int nf = 0; nf < 4; nf++) {
      int col = wn * 64 + nf * 16 + rr;
      float bias = b1[col];
#pragma unroll
      for (int j = 0; j < 4; j++) {
        int row = r0 + wm * 64 + mf * 16 + kg * 4 + j;
        if (row < N_NODES) {
          float z = acc[mf][nf][j] + bias;
          z = fmaxf(z, 0.f);
          h1[(size_t)row * NHID + col] = f2b(z);
        }
      }
    }
  }
}

// ---------------- GEMM2 (h1@W2+b2 -> buf0 fp16), double-buffered ----------------

__global__ __launch_bounds__(256) void k_gemm2(const unsigned short* __restrict__ h1,
                                               const unsigned short* __restrict__ W2T,
                                               const float* __restrict__ b2,
                                               _Float16* __restrict__ cur0) {
  __shared__ unsigned short As[2][128 * 40];
  __shared__ unsigned short Bs[2][64 * 40];
  const int tid = threadIdx.x;
  const int r0 = blockIdx.x * 128;
  const int wave = tid >> 6, lane = tid & 63;
  const int wm = wave >> 1, wn = wave & 1;
  const int rr = lane & 15, kg = lane >> 4;
  const int arow = tid >> 2, aq = tid & 3;  // A rows [0,64)+[64,128)

  f32x4 acc[4][2] = {};
  int4 av0, av1, bv0;

#define G2_LOAD(K0)                                                                      \
  do {                                                                                   \
    av0 = make_int4(0, 0, 0, 0);                                                         \
    av1 = av0;                                                                           \
    if (r0 + arow < N_NODES)                                                             \
      av0 = *(const int4*)(h1 + (size_t)(r0 + arow) * NHID + (K0) + aq * 8);             \
    if (r0 + arow + 64 < N_NODES)                                                        \
      av1 = *(const int4*)(h1 + (size_t)(r0 + arow + 64) * NHID + (K0) + aq * 8);        \
    bv0 = *(const int4*)(W2T + (size_t)arow * NHID + (K0) + aq * 8);                     \
  } while (0)

#define G2_STORE(B)                                                                      \
  do {                                                                                   \
    *(int4*)&As[B][arow * 40 + aq * 8] = av0;                                            \
    *(int4*)&As[B][(arow + 64) * 40 + aq * 8] = av1;                                     \
    *(int4*)&Bs[B][arow * 40 + aq * 8] = bv0;                                            \
  } while (0)

  G2_LOAD(0);
  G2_STORE(0);
  __syncthreads();

  for (int t = 0; t < 8; t++) {
    const int cb = t & 1;
    if (t < 7) G2_LOAD((t + 1) * 32);

    short8 a[4], b[2];
#pragma unroll
    for (int mf = 0; mf < 4; mf++)
      a[mf] = *(const short8*)&As[cb][(wm * 64 + mf * 16 + rr) * 40 + kg * 8];
#pragma unroll
    for (int nf = 0; nf < 2; nf++)
      b[nf] = *(const short8*)&Bs[cb][(wn * 32 + nf * 16 + rr) * 40 + kg * 8];
#pragma unroll
    for (int mf = 0; mf < 4; mf++)
#pragma unroll
      for (int nf = 0; nf < 2; nf++)
        acc[mf][nf] = __builtin_amdgcn_mfma_f32_16x16x32_bf16(a[mf], b[nf], acc[mf][nf], 0, 0, 0);

    if (t < 7) G2_STORE(cb ^ 1);
    __syncthreads();
  }

#pragma unroll
  for (int mf = 0; mf < 4; mf++) {
#pragma unroll
    for (int nf = 0; nf < 2; nf++) {
      int col = wn * 32 + nf * 16 + rr;
      float bias = b2[col];
#pragma unroll
      for (int j = 0; j < 4; j++) {
        int row = r0 + wm * 64 + mf * 16 + kg * 4 + j;
        if (row < N_NODES)
          cur0[(size_t)row * NCLS + col] = (_Float16)(acc[mf][nf][j] + bias);
      }
    }
  }
}

// ---------------- propagation: next = P cur (16-wide batch, readlane broadcast) ----
// one wave per node, lane = channel (C=64). Edge (src,w) broadcast via
// v_readlane_b32 (SGPR result): no LDS-pipe traffic, SGPR weight operand in FMA,
// SALU address arithmetic. Pad slots (last batch only) do w=0 * own-row loads:
// same-line L1 hits. FMA order over real edges unchanged -> bitwise-identical.
// ~32 us/hop = 205 MB gather at ~6.4 TB/s from L2/L3 -- near random-gather floor.
// Tried and REJECTED:
//   R6 32-wide batch: pads ~double issued gathers (Poisson(16) degrees), slower.
//   R9 per-t uniform guards: 16 s_cbranch per batch serialize the gather issue
//   (each load trapped in its own basic block), ~2.5x slower. Pads < branches.

__global__ __launch_bounds__(256) void k_prop(const _Float16* __restrict__ cur,
                                              _Float16* __restrict__ next,
                                              const int* __restrict__ offs,
                                              const int2* __restrict__ ew,
                                              const float* __restrict__ dinv) {
  int node = blockIdx.x * 4 + (threadIdx.x >> 6);
  int lane = threadIdx.x & 63;
  if (node >= N_NODES) return;
  float di = dinv[node];
  float acc = di * di * (float)cur[(size_t)node * NCLS + lane];  // self loop
  int e0 = offs[node], e1 = offs[node + 1];
  for (int j = e0; j < e1; j += 16) {
    int idx = j + (lane & 15);
    int2 e = (idx < e1) ? ew[idx] : make_int2(node, 0);  // pad: w=0, src=node (L1-hot)
#pragma unroll
    for (int t = 0; t < 16; t++) {
      int src = __builtin_amdgcn_readlane(e.x, t);
      float w = __int_as_float(__builtin_amdgcn_readlane(e.y, t));
      acc += w * (float)cur[(size_t)src * NCLS + lane];
    }
  }
  next[(size_t)node * NCLS + lane] = (_Float16)acc;
}

// ---------------- final: hidden = sum temp[k]*buf_k, then log_softmax ----------------

__global__ __launch_bounds__(256) void k_lsm(const _Float16* __restrict__ bufs,
                                             const float* __restrict__ temp,
                                             float* __restrict__ out) {
  int node = blockIdx.x * 4 + (threadIdx.x >> 6);
  int lane = threadIdx.x & 63;
  if (node >= N_NODES) return;
  size_t off = (size_t)node * NCLS + lane;
  float v = 0.f;
#pragma unroll
  for (int k = 0; k <= KHOP; k++)
    v += temp[k] * (float)bufs[(size_t)k * BUFSZ + off];
  float m = v;
#pragma unroll
  for (int o = 32; o; o >>= 1) m = fmaxf(m, __shfl_xor(m, o, 64));
  float ex = expf(v - m);
  float s = ex;
#pragma unroll
  for (int o = 32; o; o >>= 1) s += __shfl_xor(s, o, 64);
  out[off] = v - m - logf(s);
}

// ---------------- launch ----------------

extern "C" void kernel_launch(void* const* d_in, const int* in_sizes, int n_in,
                              void* d_out, int out_size, void* d_ws, size_t ws_size,
                              hipStream_t stream) {
  const float* x = (const float*)d_in[0];
  const int* ei = (const int*)d_in[1];  // [2, E] int32
  const float* W1 = (const float*)d_in[2];
  const float* b1 = (const float*)d_in[3];
  const float* W2 = (const float*)d_in[4];
  const float* b2 = (const float*)d_in[5];
  const float* temp = (const float*)d_in[6];
  float* out = (float*)d_out;

  char* p = (char*)d_ws;
  unsigned short* h1 = (unsigned short*)p; p += (size_t)N_NODES * NHID * 2;  // 51.2 MB
  _Float16* bufs = (_Float16*)p; p += (KHOP + 1) * BUFSZ * 2;                // 140.8 MB
  int* counts = (int*)p; p += 400128;
  int* offs = (int*)p; p += 400128;
  int* cursor = (int*)p; p += 400128;
  float* dinv = (float*)p; p += 400128;
  int* partials = (int*)p; p += 512;
  unsigned short* W1T = (unsigned short*)p; p += (size_t)NHID * NFEAT * 2;   // 256 KB
  unsigned short* W2T = (unsigned short*)p; p += (size_t)NCLS * NHID * 2;    // 32 KB
  int2* ew = (int2*)p;                                                       // 12.8 MB

  const int nb_nodes = (N_NODES + 255) / 256;   // 391
  const int nb_edges = N_EDGES / 256;           // 6250

  k_zero<<<nb_nodes, 256, 0, stream>>>(counts);
  k_count<<<nb_edges, 256, 0, stream>>>(ei + N_EDGES, counts);
  k_reduce<<<NPART, 256, 0, stream>>>(counts, partials);
  k_scanp<<<1, 128, 0, stream>>>(partials, offs);
  k_scatter<<<NPART, 256, 0, stream>>>(counts, partials, offs, cursor);
  k_dinv<<<nb_nodes, 256, 0, stream>>>(counts, dinv);
  k_fill<<<nb_edges, 256, 0, stream>>>(ei, dinv, cursor, ew);

  dim3 gt1(NFEAT / 32, NHID / 32);  // (16, 8)
  k_trans<<<gt1, 256, 0, stream>>>(W1, W1T, NFEAT, NHID);
  dim3 gt2(NHID / 32, NCLS / 32);   // (8, 2)
  k_trans<<<gt2, 256, 0, stream>>>(W2, W2T, NHID, NCLS);

  k_gemm1<<<(N_NODES + 127) / 128, 512, 0, stream>>>(x, W1T, b1, h1);
  k_gemm2<<<(N_NODES + 127) / 128, 256, 0, stream>>>(h1, W2T, b2, bufs);

  for (int k = 0; k < KHOP; k++)
    k_prop<<<(N_NODES + 3) / 4, 256, 0, stream>>>(bufs + (size_t)k * BUFSZ,
                                                  bufs + (size_t)(k + 1) * BUFSZ,
                                                  offs, ew, dinv);

  k_lsm<<<(N_NODES + 3) / 4, 256, 0, stream>>>(bufs, temp, out);
}

// Round 12
// 652.181 us; speedup vs baseline: 1.0203x; 1.0203x over previous
//
#include <hip/hip_runtime.h>
#include <hip/hip_bf16.h>

#define N_NODES 100000
#define N_EDGES 1600000
#define NFEAT 512
#define NHID 256
#define NCLS 64
#define KHOP 10
#define NPART 98  // (N_NODES + 1023) / 1024
#define BUFSZ ((size_t)N_NODES * NCLS)

typedef __attribute__((ext_vector_type(8))) short short8;
typedef __attribute__((ext_vector_type(4))) float f32x4;

__device__ __forceinline__ unsigned short f2b(float f) {
  union { float f; unsigned u; } v; v.f = f;
  unsigned r = v.u + 0x7FFFu + ((v.u >> 16) & 1u);
  return (unsigned short)(r >> 16);
}

// ---------------- graph preprocessing ----------------

__global__ __launch_bounds__(256) void k_zero(int* __restrict__ counts) {
  int i = blockIdx.x * 256 + threadIdx.x;
  if (i < N_NODES) counts[i] = 0;
}

__global__ __launch_bounds__(256) void k_count(const int* __restrict__ col,
                                               int* __restrict__ counts) {
  int e = blockIdx.x * 256 + threadIdx.x;
  if (e < N_EDGES) atomicAdd(&counts[col[e]], 1);
}

// ---- 3-phase coalesced exclusive scan of counts -> offs/cursor (+dinv fused) ----

__global__ __launch_bounds__(256) void k_reduce(const int* __restrict__ counts,
                                                int* __restrict__ partials) {
  int base = blockIdx.x * 1024 + threadIdx.x * 4;
  int4 c = make_int4(0, 0, 0, 0);
  if (base < N_NODES) c = *(const int4*)(counts + base);  // N % 4 == 0
  int s = c.x + c.y + c.z + c.w;
#pragma unroll
  for (int off = 32; off; off >>= 1) s += __shfl_xor(s, off, 64);
  __shared__ int wsum[4];
  int lane = threadIdx.x & 63, wave = threadIdx.x >> 6;
  if (lane == 0) wsum[wave] = s;
  __syncthreads();
  if (threadIdx.x == 0) partials[blockIdx.x] = wsum[0] + wsum[1] + wsum[2] + wsum[3];
}

__global__ __launch_bounds__(128) void k_scanp(int* __restrict__ partials,
                                               int* __restrict__ offs) {
  __shared__ int sm[128];
  int t = threadIdx.x;
  int v = (t < NPART) ? partials[t] : 0;
  sm[t] = v;
  __syncthreads();
  for (int off = 1; off < 128; off <<= 1) {
    int u = (t >= off) ? sm[t - off] : 0;
    __syncthreads();
    sm[t] += u;
    __syncthreads();
  }
  if (t < NPART) partials[t] = sm[t] - v;  // exclusive block prefix
  if (t == NPART - 1) offs[N_NODES] = sm[t];
}

// local exclusive scan + block prefix -> offs/cursor; dinv fused (counts in regs)
__global__ __launch_bounds__(256) void k_scatter(const int* __restrict__ counts,
                                                 const int* __restrict__ partials,
                                                 int* __restrict__ offs,
                                                 int* __restrict__ cursor,
                                                 float* __restrict__ dinv) {
  int t = threadIdx.x;
  int base = blockIdx.x * 1024 + t * 4;
  bool valid = base < N_NODES;
  int4 c = make_int4(0, 0, 0, 0);
  if (valid) c = *(const int4*)(counts + base);
  int s = c.x + c.y + c.z + c.w;
  int lane = t & 63, wave = t >> 6;
  int inc = s;
#pragma unroll
  for (int off = 1; off < 64; off <<= 1) {
    int u = __shfl_up(inc, off, 64);
    if (lane >= off) inc += u;
  }
  __shared__ int wsum[4];
  if (lane == 63) wsum[wave] = inc;
  __syncthreads();
  int pre = partials[blockIdx.x] + (inc - s);
  for (int w = 0; w < wave; w++) pre += wsum[w];
  if (valid) {
    int4 o;
    o.x = pre;
    o.y = o.x + c.x;
    o.z = o.y + c.y;
    o.w = o.z + c.z;
    *(int4*)(offs + base) = o;
    *(int4*)(cursor + base) = o;
    float4 dv;
    dv.x = rsqrtf((float)(c.x + 1));  // +1 self loop
    dv.y = rsqrtf((float)(c.y + 1));
    dv.z = rsqrtf((float)(c.z + 1));
    dv.w = rsqrtf((float)(c.w + 1));
    *(float4*)(dinv + base) = dv;
  }
}

__global__ __launch_bounds__(256) void k_fill(const int* __restrict__ ei,
                                              const float* __restrict__ dinv,
                                              int* __restrict__ cursor,
                                              int2* __restrict__ ew) {
  int e = blockIdx.x * 256 + threadIdx.x;
  if (e >= N_EDGES) return;
  int r = ei[e];
  int c = ei[N_EDGES + e];
  float w = dinv[r] * dinv[c];
  int p = atomicAdd(&cursor[c], 1);
  ew[p] = make_int2(r, __float_as_int(w));
}

// ------- transpose f32 [R][C] -> bf16 [C][R], both weights in ONE launch -------
// blocks 0..127: W1 (16x8 tiles of 32x32); blocks 128..143: W2 (8x2 tiles).

__global__ __launch_bounds__(256) void k_trans2(const float* __restrict__ W1,
                                                const float* __restrict__ W2,
                                                unsigned short* __restrict__ W1T,
                                                unsigned short* __restrict__ W2T) {
  __shared__ float sm[32][33];
  int bx = blockIdx.x;
  const float* in; unsigned short* out; int R, C, tr0, tc0;
  if (bx < 128) { in = W1; out = W1T; R = NFEAT; C = NHID; tr0 = (bx >> 3) * 32; tc0 = (bx & 7) * 32; }
  else { int b = bx - 128; in = W2; out = W2T; R = NHID; C = NCLS; tr0 = (b >> 1) * 32; tc0 = (b & 1) * 32; }
#pragma unroll
  for (int i = 0; i < 4; i++) {
    int idx = threadIdx.x + i * 256;
    int r = idx >> 5, c = idx & 31;
    sm[r][c] = in[(size_t)(tr0 + r) * C + tc0 + c];
  }
  __syncthreads();
#pragma unroll
  for (int i = 0; i < 4; i++) {
    int idx = threadIdx.x + i * 256;
    int c = idx >> 5, r = idx & 31;
    out[(size_t)(tc0 + c) * R + tr0 + r] = f2b(sm[r][c]);
  }
}

// ---------------- MLP: GEMM1 (x@W1+b1, relu -> bf16 h1) ----------------
// BM=128, BN=256 (full hidden), BK=32; 8 waves (2x4), wave tile 64x64.
// Double-buffered LDS, 1-ahead register prefetch, single barrier per K-step.
// LDS stride 40 (80B rows, 16B-aligned for b128). Tried and REJECTED:
//   R6 depth-2 reg pipeline: VGPR 56->76, occ 33->18.5%, slower.
//   R9 stride 34 (68B rows): breaks ds_*_b128 16B alignment, slower.
//   R11 single-buffer (30.7KB, 4 blocks/CU): barrier serialization, 665 vs 656.
// gemm1 ~110us is structural for this tile shape (4 structures tried).

__global__ __launch_bounds__(512) void k_gemm1(const float* __restrict__ x,
                                               const unsigned short* __restrict__ W1T,
                                               const float* __restrict__ b1,
                                               unsigned short* __restrict__ h1) {
  __shared__ unsigned short As[2][128 * 40];
  __shared__ unsigned short Bs[2][256 * 40];
  const int tid = threadIdx.x;
  const int r0 = blockIdx.x * 128;
  const int wave = tid >> 6, lane = tid & 63;
  const int wm = wave >> 2, wn = wave & 3;
  const int rr = lane & 15, kg = lane >> 4;
  const int arow = tid >> 3, akq = tid & 7;  // A rows [0,64)+[64,128)
  const int brow = tid >> 2, bq = tid & 3;   // B rows [0,128)+[128,256)

  f32x4 acc[4][4] = {};
  float4 av0, av1;
  int4 bv0, bv1;

#define G1_LOAD(K0)                                                                      \
  do {                                                                                   \
    av0 = make_float4(0.f, 0.f, 0.f, 0.f);                                               \
    av1 = av0;                                                                           \
    if (r0 + arow < N_NODES)                                                             \
      av0 = *(const float4*)(x + (size_t)(r0 + arow) * NFEAT + (K0) + akq * 4);          \
    if (r0 + arow + 64 < N_NODES)                                                        \
      av1 = *(const float4*)(x + (size_t)(r0 + arow + 64) * NFEAT + (K0) + akq * 4);     \
    bv0 = *(const int4*)(W1T + (size_t)brow * NFEAT + (K0) + bq * 8);                    \
    bv1 = *(const int4*)(W1T + (size_t)(brow + 128) * NFEAT + (K0) + bq * 8);            \
  } while (0)

#define G1_STORE(B)                                                                      \
  do {                                                                                   \
    uint2 p0, p1;                                                                        \
    p0.x = (unsigned)f2b(av0.x) | ((unsigned)f2b(av0.y) << 16);                          \
    p0.y = (unsigned)f2b(av0.z) | ((unsigned)f2b(av0.w) << 16);                          \
    p1.x = (unsigned)f2b(av1.x) | ((unsigned)f2b(av1.y) << 16);                          \
    p1.y = (unsigned)f2b(av1.z) | ((unsigned)f2b(av1.w) << 16);                          \
    *(uint2*)&As[B][arow * 40 + akq * 4] = p0;                                           \
    *(uint2*)&As[B][(arow + 64) * 40 + akq * 4] = p1;                                    \
    *(int4*)&Bs[B][brow * 40 + bq * 8] = bv0;                                            \
    *(int4*)&Bs[B][(brow + 128) * 40 + bq * 8] = bv1;                                    \
  } while (0)

  G1_LOAD(0);
  G1_STORE(0);
  __syncthreads();

  for (int t = 0; t < 16; t++) {
    const int cb = t & 1;
    if (t < 15) G1_LOAD((t + 1) * 32);  // issue next tile's global loads

    short8 a[4], b[4];
#pragma unroll
    for (int mf = 0; mf < 4; mf++)
      a[mf] = *(const short8*)&As[cb][(wm * 64 + mf * 16 + rr) * 40 + kg * 8];
#pragma unroll
    for (int nf = 0; nf < 4; nf++)
      b[nf] = *(const short8*)&Bs[cb][(wn * 64 + nf * 16 + rr) * 40 + kg * 8];
#pragma unroll
    for (int mf = 0; mf < 4; mf++)
#pragma unroll
      for (int nf = 0; nf < 4; nf++)
        acc[mf][nf] = __builtin_amdgcn_mfma_f32_16x16x32_bf16(a[mf], b[nf], acc[mf][nf], 0, 0, 0);

    if (t < 15) G1_STORE(cb ^ 1);  // convert + write alternate buffer
    __syncthreads();
  }

  // epilogue: +b1, relu, bf16 store
#pragma unroll
  for (int mf = 0; mf < 4; mf++) {
#pragma unroll
    for (int nf = 0; nf < 4; nf++) {
      int col = wn * 64 + nf * 16 + rr;
      float bias = b1[col];
#pragma unroll
      for (int j = 0; j < 4; j++) {
        int row = r0 + wm * 64 + mf * 16 + kg * 4 + j;
        if (row < N_NODES) {
          float z = acc[mf][nf][j] + bias;
          z = fmaxf(z, 0.f);
          h1[(size_t)row * NHID + col] = f2b(z);
        }
      }
    }
  }
}

// ---------------- GEMM2 (h1@W2+b2 -> buf0 fp16), double-buffered ----------------

__global__ __launch_bounds__(256) void k_gemm2(const unsigned short* __restrict__ h1,
                                               const unsigned short* __restrict__ W2T,
                                               const float* __restrict__ b2,
                                               _Float16* __restrict__ cur0) {
  __shared__ unsigned short As[2][128 * 40];
  __shared__ unsigned short Bs[2][64 * 40];
  const int tid = threadIdx.x;
  const int r0 = blockIdx.x * 128;
  const int wave = tid >> 6, lane = tid & 63;
  const int wm = wave >> 1, wn = wave & 1;
  const int rr = lane & 15, kg = lane >> 4;
  const int arow = tid >> 2, aq = tid & 3;  // A rows [0,64)+[64,128)

  f32x4 acc[4][2] = {};
  int4 av0, av1, bv0;

#define G2_LOAD(K0)                                                                      \
  do {                                                                                   \
    av0 = make_int4(0, 0, 0, 0);                                                         \
    av1 = av0;                                                                           \
    if (r0 + arow < N_NODES)                                                             \
      av0 = *(const int4*)(h1 + (size_t)(r0 + arow) * NHID + (K0) + aq * 8);             \
    if (r0 + arow + 64 < N_NODES)                                                        \
      av1 = *(const int4*)(h1 + (size_t)(r0 + arow + 64) * NHID + (K0) + aq * 8);        \
    bv0 = *(const int4*)(W2T + (size_t)arow * NHID + (K0) + aq * 8);                     \
  } while (0)

#define G2_STORE(B)                                                                      \
  do {                                                                                   \
    *(int4*)&As[B][arow * 40 + aq * 8] = av0;                                            \
    *(int4*)&As[B][(arow + 64) * 40 + aq * 8] = av1;                                     \
    *(int4*)&Bs[B][arow * 40 + aq * 8] = bv0;                                            \
  } while (0)

  G2_LOAD(0);
  G2_STORE(0);
  __syncthreads();

  for (int t = 0; t < 8; t++) {
    const int cb = t & 1;
    if (t < 7) G2_LOAD((t + 1) * 32);

    short8 a[4], b[2];
#pragma unroll
    for (int mf = 0; mf < 4; mf++)
      a[mf] = *(const short8*)&As[cb][(wm * 64 + mf * 16 + rr) * 40 + kg * 8];
#pragma unroll
    for (int nf = 0; nf < 2; nf++)
      b[nf] = *(const short8*)&Bs[cb][(wn * 32 + nf * 16 + rr) * 40 + kg * 8];
#pragma unroll
    for (int mf = 0; mf < 4; mf++)
#pragma unroll
      for (int nf = 0; nf < 2; nf++)
        acc[mf][nf] = __builtin_amdgcn_mfma_f32_16x16x32_bf16(a[mf], b[nf], acc[mf][nf], 0, 0, 0);

    if (t < 7) G2_STORE(cb ^ 1);
    __syncthreads();
  }

#pragma unroll
  for (int mf = 0; mf < 4; mf++) {
#pragma unroll
    for (int nf = 0; nf < 2; nf++) {
      int col = wn * 32 + nf * 16 + rr;
      float bias = b2[col];
#pragma unroll
      for (int j = 0; j < 4; j++) {
        int row = r0 + wm * 64 + mf * 16 + kg * 4 + j;
        if (row < N_NODES)
          cur0[(size_t)row * NCLS + col] = (_Float16)(acc[mf][nf][j] + bias);
      }
    }
  }
}

// ---------------- propagation: next = P cur (16-wide batch, readlane broadcast) ----
// one wave per node, lane = channel (C=64). Edge (src,w) broadcast via
// v_readlane_b32 (SGPR result): no LDS-pipe traffic, SGPR weight operand in FMA,
// SALU address arithmetic. Pad slots (last batch only) do w=0 * own-row loads:
// same-line L1 hits. FMA order over real edges unchanged -> bitwise-identical.
// ~32 us/hop = 205 MB gather at ~6.4 TB/s from L2/L3 -- at the random-gather
// request-rate floor (~50G req/s of 128B lines). Tried and REJECTED:
//   R6 32-wide batch: pads ~double issued gathers (Poisson(16) degrees), slower.
//   R9 per-t uniform guards: 16 s_cbranch per batch serialize the gather issue
//   (each load trapped in its own basic block), ~2.5x slower. Pads < branches.
//   (channel-split L2-resident variant analyzed: outstanding-request capacity
//   drops 4x, request count unchanged -> not a clear win, shelved.)

__global__ __launch_bounds__(256) void k_prop(const _Float16* __restrict__ cur,
                                              _Float16* __restrict__ next,
                                              const int* __restrict__ offs,
                                              const int2* __restrict__ ew,
                                              const float* __restrict__ dinv) {
  int node = blockIdx.x * 4 + (threadIdx.x >> 6);
  int lane = threadIdx.x & 63;
  if (node >= N_NODES) return;
  float di = dinv[node];
  float acc = di * di * (float)cur[(size_t)node * NCLS + lane];  // self loop
  int e0 = offs[node], e1 = offs[node + 1];
  for (int j = e0; j < e1; j += 16) {
    int idx = j + (lane & 15);
    int2 e = (idx < e1) ? ew[idx] : make_int2(node, 0);  // pad: w=0, src=node (L1-hot)
#pragma unroll
    for (int t = 0; t < 16; t++) {
      int src = __builtin_amdgcn_readlane(e.x, t);
      float w = __int_as_float(__builtin_amdgcn_readlane(e.y, t));
      acc += w * (float)cur[(size_t)src * NCLS + lane];
    }
  }
  next[(size_t)node * NCLS + lane] = (_Float16)acc;
}

// ---------------- final: hidden = sum temp[k]*buf_k, then log_softmax ----------------

__global__ __launch_bounds__(256) void k_lsm(const _Float16* __restrict__ bufs,
                                             const float* __restrict__ temp,
                                             float* __restrict__ out) {
  int node = blockIdx.x * 4 + (threadIdx.x >> 6);
  int lane = threadIdx.x & 63;
  if (node >= N_NODES) return;
  size_t off = (size_t)node * NCLS + lane;
  float v = 0.f;
#pragma unroll
  for (int k = 0; k <= KHOP; k++)
    v += temp[k] * (float)bufs[(size_t)k * BUFSZ + off];
  float m = v;
#pragma unroll
  for (int o = 32; o; o >>= 1) m = fmaxf(m, __shfl_xor(m, o, 64));
  float ex = expf(v - m);
  float s = ex;
#pragma unroll
  for (int o = 32; o; o >>= 1) s += __shfl_xor(s, o, 64);
  out[off] = v - m - logf(s);
}

// ---------------- launch ----------------

extern "C" void kernel_launch(void* const* d_in, const int* in_sizes, int n_in,
                              void* d_out, int out_size, void* d_ws, size_t ws_size,
                              hipStream_t stream) {
  const float* x = (const float*)d_in[0];
  const int* ei = (const int*)d_in[1];  // [2, E] int32
  const float* W1 = (const float*)d_in[2];
  const float* b1 = (const float*)d_in[3];
  const float* W2 = (const float*)d_in[4];
  const float* b2 = (const float*)d_in[5];
  const float* temp = (const float*)d_in[6];
  float* out = (float*)d_out;

  char* p = (char*)d_ws;
  unsigned short* h1 = (unsigned short*)p; p += (size_t)N_NODES * NHID * 2;  // 51.2 MB
  _Float16* bufs = (_Float16*)p; p += (KHOP + 1) * BUFSZ * 2;                // 140.8 MB
  int* counts = (int*)p; p += 400128;
  int* offs = (int*)p; p += 400128;
  int* cursor = (int*)p; p += 400128;
  float* dinv = (float*)p; p += 400128;
  int* partials = (int*)p; p += 512;
  unsigned short* W1T = (unsigned short*)p; p += (size_t)NHID * NFEAT * 2;   // 256 KB
  unsigned short* W2T = (unsigned short*)p; p += (size_t)NCLS * NHID * 2;    // 32 KB
  int2* ew = (int2*)p;                                                       // 12.8 MB

  const int nb_nodes = (N_NODES + 255) / 256;   // 391
  const int nb_edges = N_EDGES / 256;           // 6250

  k_zero<<<nb_nodes, 256, 0, stream>>>(counts);
  k_count<<<nb_edges, 256, 0, stream>>>(ei + N_EDGES, counts);
  k_reduce<<<NPART, 256, 0, stream>>>(counts, partials);
  k_scanp<<<1, 128, 0, stream>>>(partials, offs);
  k_scatter<<<NPART, 256, 0, stream>>>(counts, partials, offs, cursor, dinv);
  k_fill<<<nb_edges, 256, 0, stream>>>(ei, dinv, cursor, ew);

  k_trans2<<<144, 256, 0, stream>>>(W1, W2, W1T, W2T);

  k_gemm1<<<(N_NODES + 127) / 128, 512, 0, stream>>>(x, W1T, b1, h1);
  k_gemm2<<<(N_NODES + 127) / 128, 256, 0, stream>>>(h1, W2T, b2, bufs);

  for (int k = 0; k < KHOP; k++)
    k_prop<<<(N_NODES + 3) / 4, 256, 0, stream>>>(bufs + (size_t)k * BUFSZ,
                                                  bufs + (size_t)(k + 1) * BUFSZ,
                                                  offs, ew, dinv);

  k_lsm<<<(N_NODES + 3) / 4, 256, 0, stream>>>(bufs, temp, out);
}